// Round 1
// baseline (3224.530 us; speedup 1.0000x reference)
//
#include <hip/hip_runtime.h>
#include <math.h>

#define BB 32
#define NN 5000
#define EE 500
#define AT 50
#define TTT 4
#define ITT 24
#define FT 384
#define FI 383
#define KH 100
#define BN (BB*NN)

__device__ __forceinline__ float leaky(float x){ return x > 0.f ? x : 0.1f*x; }
__device__ __forceinline__ float sigm(float x){ return 1.f/(1.f+__expf(-x)); }

// workspace offsets (in floats)
enum : size_t {
  O_WTT = 0,          // 19200  W_text^T [f*50+d]
  O_WIT = 19200,      // 19150  W_img^T
  O_WIP = 38352,      // 10000  W_iproj*g, [(t*50+d)*50+o]
  O_WTP = 48352,      // 60000  W_tproj*g, [(i*50+d)*50+o]
  O_W1T = 108352,     // 50000  W1[:, :E]^T [e*100+k]
  O_W3T = 158352,     // 50000  W3^T [k*500+e]
  O_SIP = 208352,     // 200    sum_d Wg_iproj  [t*50+o]
  O_STP = 208552,     // 1200   sum_d Wg_tproj  [i*50+o]
  O_CBI = 209752,     // 50     2*sum(lnb*W_iproj)+b_iproj
  O_CBT = 209802,     // 50
  O_RGI = 209856,     // 3072   sigmoid(rel@Wrel1^T+b) [b*96+it]
  O_RGT = 212928,     // 3072
  O_RB  = 216000,     // 3200   rel@W1[:,E:]^T [b*100+k]
  O_A   = 219200,     // 500000 ent@W1[:,:E]^T [n*100+k]
  O_PT  = 719200,     // 16000  pos_t [b*500+e]
  O_PTN = 735200,     // 32
  O_PIM = 735232,     // 1600   pos_img [b*50+o]
  O_PIMN= 736832,     // 32
  O_PTX = 736864,     // 1600
  O_PTXN= 738464,     // 32
  O_NUM = 738496,     // 160000 t_att . pos_t  [b*NN+n]
  O_SQ  = 898496,     // 160000 |t_att|^2
  O_MR  = 1058496,    // 96     softmax logit max [a*32+b]
  O_SR  = 1058592,    // 96     softmax denom
  O_IA  = 1058688,    // 8000000 img_att_all [(b*NN+n)*50+o]
  O_TA  = 9058688,    // 8000000 text_att_all
};

// ---------------- weight preprocessing ----------------
__global__ void k_prep(const float* Wt, const float* Wi, const float* Wip, const float* Wtp,
                       const float* W1, const float* W3, const float* g, const float* lb,
                       const float* bip, const float* btp, float* ws){
  int id = blockIdx.x*256 + threadIdx.x;
  if (id < 19200){ int d=id%50, f=id/50; ws[O_WTT+id] = Wt[d*FT+f]; return; }
  id -= 19200;
  if (id < 19150){ int d=id%50, f=id/50; ws[O_WIT+id] = Wi[d*FI+f]; return; }
  id -= 19150;
  if (id < 10000){ int o=id%50, r=id/50, d=r%50; ws[O_WIP+id] = Wip[o*200+r]*g[d]; return; }
  id -= 10000;
  if (id < 60000){ int o=id%50, r=id/50, d=r%50; ws[O_WTP+id] = Wtp[o*1200+r]*g[d]; return; }
  id -= 60000;
  if (id < 50000){ int k=id%100, e=id/100; ws[O_W1T+id] = W1[k*1000+e]; return; }
  id -= 50000;
  if (id < 50000){ int e=id%500, k=id/500; ws[O_W3T+id] = W3[e*100+k]; return; }
  id -= 50000;
  if (id < 200){ int o=id%50, t=id/50; float s=0; for(int d=0;d<50;d++) s += Wip[o*200+t*50+d]*g[d]; ws[O_SIP+id]=s; return; }
  id -= 200;
  if (id < 1200){ int o=id%50, i=id/50; float s=0; for(int d=0;d<50;d++) s += Wtp[o*1200+i*50+d]*g[d]; ws[O_STP+id]=s; return; }
  id -= 1200;
  if (id < 50){ int o=id; float s=0; for(int j=0;j<200;j++) s += lb[j%50]*Wip[o*200+j]; ws[O_CBI+o]=2.f*s+bip[o]; return; }
  id -= 50;
  if (id < 50){ int o=id; float s=0; for(int j=0;j<1200;j++) s += lb[j%50]*Wtp[o*1200+j]; ws[O_CBT+o]=2.f*s+btp[o]; return; }
}

// ---------------- per-batch relation gates ----------------
__global__ void k_rel(const int* ps, const float* rele, const float* Wr1, const float* br1,
                      const float* Wr2, const float* br2, const float* W1, float* ws){
  __shared__ float relL[EE];
  int b = blockIdx.x;
  int r = ps[b*3+1];
  for (int e=threadIdx.x; e<EE; e+=256) relL[e] = rele[(size_t)r*EE+e];
  __syncthreads();
  for (int j=threadIdx.x; j<292; j+=256){
    if (j<96){
      float a=br1[j]; const float* w=&Wr1[j*EE];
      for(int e=0;e<EE;e++) a+=relL[e]*w[e];
      ws[O_RGI+b*96+j]=sigm(a);
    } else if (j<192){
      int jj=j-96; float a=br2[jj]; const float* w=&Wr2[jj*EE];
      for(int e=0;e<EE;e++) a+=relL[e]*w[e];
      ws[O_RGT+b*96+jj]=sigm(a);
    } else {
      int k=j-192; float a=0; const float* w=&W1[k*1000+500];
      for(int e=0;e<EE;e++) a+=relL[e]*w[e];
      ws[O_RB+b*100+k]=a;
    }
  }
}

// ---------------- A[n,k] = ent @ W1[:, :E]^T ----------------
__global__ void k_A(const float* ent, float* ws){
  __shared__ float entL[8*EE];
  int n0 = blockIdx.x*8;
  for (int idx=threadIdx.x; idx<8*EE; idx+=256) entL[idx] = ent[(size_t)n0*EE + idx];
  __syncthreads();
  const float* W1T = &ws[O_W1T];
  for (int idx=threadIdx.x; idx<800; idx+=256){
    int rr=idx/100, k=idx%100; float a=0;
    const float* el=&entL[rr*EE];
    for (int e=0;e<EE;e++) a += el[e]*W1T[e*100+k];
    ws[O_A + (size_t)(n0+rr)*100 + k] = a;
  }
}

// ---------------- pos_t vectors (needed before the gate reduction) ----------------
__global__ void k_pos(const int* ps, const float* ent, const float* b1, const float* b3, float* ws){
  __shared__ float hL[KH];
  __shared__ float red[4];
  int b=blockIdx.x; int n=ps[b*3+2]; int tid=threadIdx.x;
  if (tid<KH) hL[tid] = leaky(ws[O_A+(size_t)n*100+tid] + ws[O_RB+b*100+tid] + b1[tid]);
  __syncthreads();
  const float* w3t=&ws[O_W3T];
  float sq=0;
  for (int e=tid; e<EE; e+=256){
    float a=b3[e];
    for (int k=0;k<KH;k++) a += hL[k]*w3t[k*500+e];
    float gg=sigm(a); float ta=ent[(size_t)n*EE+e]*gg;
    ws[O_PT+b*500+e]=ta; sq+=ta*ta;
  }
  for (int off=1; off<64; off<<=1) sq += __shfl_xor(sq, off);
  if ((tid&63)==0) red[tid>>6]=sq;
  __syncthreads();
  if (tid==0) ws[O_PTN+b] = sqrtf(red[0]+red[1]+red[2]+red[3]);
}

// ---------------- the big fused per-n kernel ----------------
__global__ __launch_bounds__(256) void k_pern(const float* etg, const float* eig,
                                              const float* btx, const float* bim, float* ws){
  __shared__ float te[TTT*AT];               // text_emb [t*50+d]
  __shared__ float ie[ITT*AT];               // img_emb  [i*50+d]
  __shared__ float cr[ITT*TTT];              // cross [i*4+t]
  __shared__ float mimg[ITT], mtxt[TTT];
  __shared__ float Gi[ITT*ITT];
  __shared__ float Gt[TTT*TTT];
  __shared__ __align__(16) float ipb[ITT*AT*TTT];  // [(i*50+o)*4+t]
  __shared__ __align__(16) float tpb[ITT*AT*TTT];
  __shared__ __align__(16) float aimg[ITT*TTT];    // softmax over i (per t)
  __shared__ __align__(16) float atxt[ITT*TTT];    // softmax over t (per i)
  __shared__ float invA1[TTT], muA1[TTT], invA2[ITT], muA2[ITT];
  __shared__ float Patt[AT], Qatt[AT];
  __shared__ float SipL[TTT*AT];
  __shared__ float CBiL[AT], CBtL[AT];
  __shared__ __align__(16) float w1s[4][ITT*TTT];
  __shared__ __align__(16) float w2s[4][ITT*TTT];
  __shared__ float inv1s[4][TTT], mu1s[4][TTT];
  __shared__ float inv2s[4][ITT], mu2s[4][ITT];

  int n = blockIdx.x, tid = threadIdx.x;

  // stage small constants
  for (int j=tid; j<200; j+=256) SipL[j]=ws[O_SIP+j];
  if (tid<50){ CBiL[tid]=ws[O_CBI+tid]; CBtL[tid]=ws[O_CBT+tid]; }

  // S1: embeddings (leaky(x@W^T + b))
  const float* WTT=&ws[O_WTT]; const float* WIT=&ws[O_WIT];
  for (int idx=tid; idx<1400; idx+=256){
    if (idx<200){
      int t=idx/50, d=idx%50;
      const float* src=&etg[((size_t)n*TTT+t)*FT];
      float a=btx[d];
      for (int f=0; f<FT; f++) a += src[f]*WTT[f*50+d];
      te[idx]=leaky(a);
    } else {
      int j=idx-200; int i=j/50, d=j%50;
      const float* src=&eig[((size_t)n*ITT+i)*FI];
      float a=bim[d];
      for (int f=0; f<FI; f++) a += src[f]*WIT[f*50+d];
      ie[j]=leaky(a);
    }
  }
  __syncthreads();

  // S2: cross, means, Gram matrices
  if (tid<96){
    int i=tid>>2, t=tid&3; float s=0;
    for(int d=0;d<50;d++) s+=ie[i*50+d]*te[t*50+d];
    cr[tid]=s;
  } else if (tid<120){
    int i=tid-96; float s=0; for(int d=0;d<50;d++) s+=ie[i*50+d]; mimg[i]=s*0.02f;
  } else if (tid<124){
    int t=tid-120; float s=0; for(int d=0;d<50;d++) s+=te[t*50+d]; mtxt[t]=s*0.02f;
  } else if (tid<140){
    int q=tid-124; int t=q>>2,u=q&3; float s=0;
    for(int d=0;d<50;d++) s+=te[t*50+d]*te[u*50+d];
    Gt[q]=s;
  }
  for (int idx=tid; idx<576; idx+=256){
    int i=idx/24, j2=idx%24; float s=0;
    for(int d=0;d<50;d++) s+=ie[i*50+d]*ie[j2*50+d];
    Gi[idx]=s;
  }
  __syncthreads();

  // S3: pre-projected tensors  ipb = emb_img . Wg_iproj_t ; tpb = emb_text . Wg_tproj_i
  const float* WIP=&ws[O_WIP]; const float* WTP=&ws[O_WTP];
  for (int idx=tid; idx<1200; idx+=256){
    int i=idx/50, o=idx%50;
    float x0=0,x1=0,x2=0,x3=0;
    for (int d=0; d<50; d++){
      float v=ie[i*50+d];
      x0+=v*WIP[(     d)*50+o];
      x1+=v*WIP[( 50+d)*50+o];
      x2+=v*WIP[(100+d)*50+o];
      x3+=v*WIP[(150+d)*50+o];
    }
    *(float4*)&ipb[idx*4] = make_float4(x0,x1,x2,x3);
    float y0=0,y1=0,y2=0,y3=0;
    for (int d=0; d<50; d++){
      float wv=WTP[(i*50+d)*50+o];
      y0+=te[d]*wv; y1+=te[50+d]*wv; y2+=te[100+d]*wv; y3+=te[150+d]*wv;
    }
    *(float4*)&tpb[idx*4] = make_float4(y0,y1,y2,y3);
  }
  // softmax weights + att-path LN stats (each thread reads only its own writes)
  if (tid<4){
    int t=tid;
    float mx=-1e30f; for(int i=0;i<24;i++) mx=fmaxf(mx, cr[i*4+t]);
    float s=0; for(int i=0;i<24;i++) s+=__expf(cr[i*4+t]-mx);
    float invs=1.f/s;
    for(int i=0;i<24;i++) aimg[i*4+t]=__expf(cr[i*4+t]-mx)*invs;
    float mu=0; for(int i=0;i<24;i++) mu+=aimg[i*4+t]*mimg[i];
    float q=0;
    for(int i=0;i<24;i++){ float s2=0; for(int j=0;j<24;j++) s2+=Gi[i*24+j]*aimg[j*4+t]; q+=aimg[i*4+t]*s2; }
    invA1[t]=rsqrtf(q*0.02f-mu*mu+1e-5f); muA1[t]=mu;
  } else if (tid>=32 && tid<56){
    int i=tid-32;
    float mx=-1e30f; for(int t=0;t<4;t++) mx=fmaxf(mx, cr[i*4+t]);
    float s=0; for(int t=0;t<4;t++) s+=__expf(cr[i*4+t]-mx);
    float invs=1.f/s;
    for(int t=0;t<4;t++) atxt[i*4+t]=__expf(cr[i*4+t]-mx)*invs;
    float mu=0; for(int t=0;t<4;t++) mu+=atxt[i*4+t]*mtxt[t];
    float q=0;
    for(int t=0;t<4;t++) for(int u=0;u<4;u++) q+=atxt[i*4+t]*atxt[i*4+u]*Gt[t*4+u];
    invA2[i]=rsqrtf(q*0.02f-mu*mu+1e-5f); muA2[i]=mu;
  }
  __syncthreads();

  // S4: B-independent projected-LN of img_att / text_att
  const float* StpG = &ws[O_STP];
  if (tid<50){
    int o=tid; float4 xw=make_float4(0,0,0,0);
    for (int i=0;i<24;i++){
      const float4 av=*(const float4*)&aimg[i*4];
      const float4 pv=*(const float4*)&ipb[(i*50+o)*4];
      xw.x+=av.x*pv.x; xw.y+=av.y*pv.y; xw.z+=av.z*pv.z; xw.w+=av.w*pv.w;
    }
    Patt[o] = invA1[0]*(xw.x-muA1[0]*SipL[o])     + invA1[1]*(xw.y-muA1[1]*SipL[50+o])
            + invA1[2]*(xw.z-muA1[2]*SipL[100+o]) + invA1[3]*(xw.w-muA1[3]*SipL[150+o]);
  } else if (tid>=64 && tid<114){
    int o=tid-64; float s=0;
    for (int i=0;i<24;i++){
      const float4 av=*(const float4*)&atxt[i*4];
      const float4 pv=*(const float4*)&tpb[(i*50+o)*4];
      float xw=av.x*pv.x+av.y*pv.y+av.z*pv.z+av.w*pv.w;
      s += invA2[i]*(xw-muA2[i]*StpG[i*50+o]);
    }
    Qatt[o]=s;
  }
  __syncthreads();

  // C: per-batch passes, 4 batches concurrently (one per wave)
  int g=tid>>6, lane=tid&63;
  float* iaG=&ws[O_IA]; float* taG=&ws[O_TA];
  const float* rgi=&ws[O_RGI]; const float* rgt=&ws[O_RGT];
  for (int rep=0; rep<8; rep++){
    int b=rep*4+g;
    // C1: weights w = rg * cross
    for (int it=lane; it<96; it+=64){
      float c=cr[it];
      w1s[g][it]=rgi[b*96+it]*c;
      w2s[g][it]=rgt[b*96+it]*c;
    }
    __syncthreads();
    // C2: LN stats.  img: q_t = w^T Gi w, mu_t = w.m   (xor-reduce over i)
    float p, pm;
    {
      int i=lane>>2, t=lane&3;
      float wv=w1s[g][lane];
      float s=0; for(int j=0;j<24;j++) s+=Gi[i*24+j]*w1s[g][j*4+t];
      p=wv*s; pm=wv*mimg[i];
    }
    if (lane<32){
      int it=lane+64; int i=it>>2, t=it&3;
      float wv=w1s[g][it];
      float s=0; for(int j=0;j<24;j++) s+=Gi[i*24+j]*w1s[g][j*4+t];
      p+=wv*s; pm+=wv*mimg[i];
    }
    p += __shfl_xor(p,4);  pm += __shfl_xor(pm,4);
    p += __shfl_xor(p,8);  pm += __shfl_xor(pm,8);
    p += __shfl_xor(p,16); pm += __shfl_xor(pm,16);
    p += __shfl_xor(p,32); pm += __shfl_xor(pm,32);
    if (lane<4){
      float mu=pm;
      inv1s[g][lane]=rsqrtf(p*0.02f-mu*mu+1e-5f); mu1s[g][lane]=mu;
    }
    if (lane<24){
      int i=lane;
      float v0=w2s[g][i*4], v1=w2s[g][i*4+1], v2=w2s[g][i*4+2], v3=w2s[g][i*4+3];
      float mu = v0*mtxt[0]+v1*mtxt[1]+v2*mtxt[2]+v3*mtxt[3];
      float q = v0*(v0*Gt[0]+v1*Gt[1]+v2*Gt[2]+v3*Gt[3])
              + v1*(v0*Gt[4]+v1*Gt[5]+v2*Gt[6]+v3*Gt[7])
              + v2*(v0*Gt[8]+v1*Gt[9]+v2*Gt[10]+v3*Gt[11])
              + v3*(v0*Gt[12]+v1*Gt[13]+v2*Gt[14]+v3*Gt[15]);
      inv2s[g][i]=rsqrtf(q*0.02f-mu*mu+1e-5f); mu2s[g][i]=mu;
    }
    __syncthreads();
    // C3: project and write
    if (lane<50){
      int o=lane;
      float4 xw=make_float4(0,0,0,0);
      for (int i=0;i<24;i++){
        const float4 wv=*(const float4*)&w1s[g][i*4];
        const float4 pv=*(const float4*)&ipb[(i*50+o)*4];
        xw.x+=wv.x*pv.x; xw.y+=wv.y*pv.y; xw.z+=wv.z*pv.z; xw.w+=wv.w*pv.w;
      }
      float si = inv1s[g][0]*(xw.x-mu1s[g][0]*SipL[o])     + inv1s[g][1]*(xw.y-mu1s[g][1]*SipL[50+o])
               + inv1s[g][2]*(xw.z-mu1s[g][2]*SipL[100+o]) + inv1s[g][3]*(xw.w-mu1s[g][3]*SipL[150+o]);
      float st=0;
      for (int i=0;i<24;i++){
        const float4 wv=*(const float4*)&w2s[g][i*4];
        const float4 pv=*(const float4*)&tpb[(i*50+o)*4];
        float xwv=wv.x*pv.x+wv.y*pv.y+wv.z*pv.z+wv.w*pv.w;
        st += inv2s[g][i]*(xwv-mu2s[g][i]*StpG[i*50+o]);
      }
      size_t base=((size_t)b*NN+n)*50+o;
      iaG[base] = si + Patt[o] + CBiL[o];
      taG[base] = st + Qatt[o] + CBtL[o];
    }
    __syncthreads();
  }
}

// ---------------- fused gate GEMM + cosine-sim reductions (t path) ----------------
__global__ __launch_bounds__(256) void k_gate(const float* ent, const float* b1, const float* b3, float* ws){
  __shared__ float entL[EE];
  __shared__ float AL[KH];
  __shared__ float hall[BB*KH];             // 3200
  __shared__ __align__(16) float w3c[KH*100]; // 10000: chunk of W3^T [k*100+j]
  __shared__ float numL[BB], sqL[BB];
  int n=blockIdx.x, tid=threadIdx.x;
  for (int e=tid;e<EE;e+=256) entL[e]=ent[(size_t)n*EE+e];
  if (tid<KH) AL[tid]=ws[O_A+(size_t)n*KH+tid];
  if (tid<BB){ numL[tid]=0.f; sqL[tid]=0.f; }
  __syncthreads();
  for (int idx=tid; idx<BB*KH; idx+=256){
    int b=idx/KH, k=idx%KH;
    hall[idx]=leaky(AL[k]+ws[O_RB+b*KH+k]+b1[k]);
  }
  __syncthreads();
  int e4=tid&31, bsub=tid>>5;
  const float* W3T=&ws[O_W3T];
  const float* PT=&ws[O_PT];
  bool val = e4<25;
  int j0=e4*4;
  for (int c=0;c<5;c++){
    int ebase=c*100;
    for (int idx=tid; idx<10000; idx+=256){
      int k=idx/100, j=idx%100;
      w3c[idx]=W3T[k*500+ebase+j];
    }
    __syncthreads();
    for (int bb=0; bb<4; bb++){
      int b=bb*8+bsub;
      float a0=0,a1=0,a2=0,a3=0;
      if (val){
        const float* hb=&hall[b*KH];
        for (int k=0;k<KH;k++){
          float hv=hb[k];
          const float4 w4=*(const float4*)&w3c[k*100+j0];
          a0+=hv*w4.x; a1+=hv*w4.y; a2+=hv*w4.z; a3+=hv*w4.w;
        }
      }
      float pn=0, psq=0;
      if (val){
        int e=ebase+j0;
        float g0=sigm(a0+b3[e+0]); float t0=entL[e+0]*g0; pn+=t0*PT[b*EE+e+0]; psq+=t0*t0;
        float g1=sigm(a1+b3[e+1]); float t1=entL[e+1]*g1; pn+=t1*PT[b*EE+e+1]; psq+=t1*t1;
        float g2=sigm(a2+b3[e+2]); float t2=entL[e+2]*g2; pn+=t2*PT[b*EE+e+2]; psq+=t2*t2;
        float g3=sigm(a3+b3[e+3]); float t3=entL[e+3]*g3; pn+=t3*PT[b*EE+e+3]; psq+=t3*t3;
      }
      for (int off=1; off<32; off<<=1){ pn+=__shfl_xor(pn,off); psq+=__shfl_xor(psq,off); }
      if (e4==0){ atomicAdd(&numL[b],pn); atomicAdd(&sqL[b],psq); }
    }
    __syncthreads();
  }
  if (tid<BB){
    ws[O_NUM + (size_t)tid*NN + n]=numL[tid];
    ws[O_SQ  + (size_t)tid*NN + n]=sqL[tid];
  }
}

// ---------------- gather pos img/text vectors + norms ----------------
__global__ void k_possim(const int* ps, float* ws){
  int b=blockIdx.x, o=threadIdx.x;
  int pos=ps[b*3+2];
  float vi=0, vt=0;
  if (o<50){
    vi=ws[O_IA+((size_t)b*NN+pos)*50+o];
    vt=ws[O_TA+((size_t)b*NN+pos)*50+o];
    ws[O_PIM+b*50+o]=vi; ws[O_PTX+b*50+o]=vt;
  }
  float si=vi*vi, st=vt*vt;
  for (int off=1;off<64;off<<=1){ si+=__shfl_xor(si,off); st+=__shfl_xor(st,off); }
  if (o==0){ ws[O_PIMN+b]=sqrtf(si); ws[O_PTXN+b]=sqrtf(st); }
}

// ---------------- cosine similarities ----------------
__global__ void k_sim(float* out, const float* ws){
  int t = blockIdx.x*256+threadIdx.x;
  if (t>=BN) return;
  int b=t/NN;
  const float* xi=&ws[O_IA+(size_t)t*50];
  const float* xt=&ws[O_TA+(size_t)t*50];
  const float* pi=&ws[O_PIM+b*50];
  const float* px=&ws[O_PTX+b*50];
  float di=0,ni=0,dt=0,nt=0;
  for (int o=0;o<50;o++){
    float a=xi[o], p=pi[o]; di+=a*p; ni+=a*a;
    float c=xt[o], q=px[o]; dt+=c*q; nt+=c*c;
  }
  out[BN   + t] = di/(sqrtf(ni)*ws[O_PIMN+b]+1e-10f);
  out[2*BN + t] = dt/(sqrtf(nt)*ws[O_PTXN+b]+1e-10f);
  out[3*BN + t] = ws[O_NUM+t]/(sqrtf(ws[O_SQ+t])*ws[O_PTN+b]+1e-10f);
}

// ---------------- softmax pass 1: max + denom per (array, b) ----------------
__global__ void k_smax1(const float* out, float* ws){
  __shared__ float red[4];
  __shared__ float Msh;
  int a=blockIdx.x>>5, b=blockIdx.x&31, tid=threadIdx.x;
  const float* arr=&out[(size_t)(1+a)*BN + (size_t)b*NN];
  float mx=-1e30f;
  for (int i=tid;i<NN;i+=256) mx=fmaxf(mx,arr[i]);
  for (int off=1;off<64;off<<=1) mx=fmaxf(mx,__shfl_xor(mx,off));
  if ((tid&63)==0) red[tid>>6]=mx;
  __syncthreads();
  if (tid==0) Msh=fmaxf(fmaxf(red[0],red[1]),fmaxf(red[2],red[3]));
  __syncthreads();
  float M2=2.f*Msh;
  float s=0;
  for (int i=tid;i<NN;i+=256) s+=__expf(2.f*arr[i]-M2);
  for (int off=1;off<64;off<<=1) s+=__shfl_xor(s,off);
  if ((tid&63)==0) red[tid>>6]=s;
  __syncthreads();
  if (tid==0){ ws[O_MR+a*32+b]=M2; ws[O_SR+a*32+b]=red[0]+red[1]+red[2]+red[3]; }
}

// ---------------- softmax pass 2: sum of three softmaxes ----------------
__global__ void k_smax2(float* out, const float* ws){
  int t=blockIdx.x*256+threadIdx.x;
  if (t>=BN) return;
  int b=t/NN;
  float r=0;
  for (int a=0;a<3;a++)
    r += __expf(2.f*out[(size_t)(1+a)*BN+t]-ws[O_MR+a*32+b])/ws[O_SR+a*32+b];
  out[t]=r;
}

extern "C" void kernel_launch(void* const* d_in, const int* in_sizes, int n_in,
                              void* d_out, int out_size, void* d_ws, size_t ws_size,
                              hipStream_t stream){
  (void)in_sizes; (void)n_in; (void)out_size; (void)ws_size;
  const int*   ps  =(const int*)  d_in[0];
  const float* etg =(const float*)d_in[1];
  const float* eig =(const float*)d_in[2];
  const float* ent =(const float*)d_in[3];
  const float* rele=(const float*)d_in[4];
  const float* Wt  =(const float*)d_in[5];
  const float* btx =(const float*)d_in[6];
  const float* Wi  =(const float*)d_in[7];
  const float* bim =(const float*)d_in[8];
  const float* Wtp =(const float*)d_in[9];
  const float* btp =(const float*)d_in[10];
  const float* Wip =(const float*)d_in[11];
  const float* bip =(const float*)d_in[12];
  const float* Wr1 =(const float*)d_in[13];
  const float* br1 =(const float*)d_in[14];
  const float* Wr2 =(const float*)d_in[15];
  const float* br2 =(const float*)d_in[16];
  const float* W1  =(const float*)d_in[17];
  const float* b1  =(const float*)d_in[18];
  const float* W3  =(const float*)d_in[19];
  const float* b3  =(const float*)d_in[20];
  const float* lng =(const float*)d_in[21];
  const float* lnb =(const float*)d_in[22];
  float* ws =(float*)d_ws;
  float* out=(float*)d_out;

  k_prep  <<<820, 256,0,stream>>>(Wt,Wi,Wip,Wtp,W1,W3,lng,lnb,bip,btp,ws);
  k_rel   <<<32,  256,0,stream>>>(ps,rele,Wr1,br1,Wr2,br2,W1,ws);
  k_A     <<<625, 256,0,stream>>>(ent,ws);
  k_pos   <<<32,  256,0,stream>>>(ps,ent,b1,b3,ws);
  k_pern  <<<5000,256,0,stream>>>(etg,eig,btx,bim,ws);
  k_gate  <<<5000,256,0,stream>>>(ent,b1,b3,ws);
  k_possim<<<32,  64, 0,stream>>>(ps,ws);
  k_sim   <<<625, 256,0,stream>>>(out,ws);
  k_smax1 <<<96,  256,0,stream>>>(out,ws);
  k_smax2 <<<625, 256,0,stream>>>(out,ws);
}

// Round 2
// 1908.455 us; speedup vs baseline: 1.6896x; 1.6896x over previous
//
#include <hip/hip_runtime.h>
#include <math.h>

#define BB 32
#define NN 5000
#define EE 500
#define AT 50
#define TTT 4
#define ITT 24
#define FT 384
#define FI 383
#define KH 100
#define BN (BB*NN)

__device__ __forceinline__ float leaky(float x){ return x > 0.f ? x : 0.1f*x; }
__device__ __forceinline__ float sigm(float x){ return 1.f/(1.f+__expf(-x)); }

// workspace offsets (floats). Total 8,023,256 floats = 32.1 MB.
enum : size_t {
  O_WTT = 0,         // 19968  W_text^T padded [f][52]
  O_WIT = 19968,     // 19968  W_img^T padded [f][52] (row 383 zero)
  O_WIP = 39936,     // 10400  W_iproj*g padded [t*50+d][52]
  O_WTP = 50336,     // 62400  W_tproj*g padded [i*50+d][52]
  O_W1T = 112736,    // 50000  W1[:, :E]^T [e][100]
  O_W3T = 162736,    // 50000  W3^T [k][500]
  O_SIP = 212736,    // 208    sum_d Wg_iproj [t][52]
  O_STP = 212944,    // 1248   sum_d Wg_tproj [i][52]
  O_CBI = 214192,    // 52     2*sum(lnb*W_iproj)+b_iproj, pad 0
  O_CBT = 214244,    // 52
  O_RGI = 214296,    // 3072   sigmoid(rel@Wrel1^T+b) [b][96]
  O_RGT = 217368,    // 3072
  O_RB  = 220440,    // 3200   rel@W1[:,E:]^T [b][100]
  O_A   = 223640,    // 500000 ent@W1[:,:E]^T [n][100]
  O_PT  = 723640,    // 16000  pos_t [b][500]
  O_PTN = 739640,    // 32
  O_PIM = 739672,    // 1664   pos_img [b][52]
  O_PIMN= 741336,    // 32
  O_PTX = 741368,    // 1664
  O_PTXN= 743032,    // 32
  O_MR  = 743064,    // 96
  O_SR  = 743160,    // 96
  O_EMB = 743256,    // 7280000 emb [n][28][52]: rows 0..3 text, 4..27 img
};

// ---------------- weight preprocessing ----------------
__global__ void k_prep(const float* Wt, const float* Wi, const float* Wip, const float* Wtp,
                       const float* W1, const float* W3, const float* g, const float* lb,
                       const float* bip, const float* btp, float* ws){
  int id = blockIdx.x*256 + threadIdx.x;
  if (id < 19968){ int f=id/52, d=id%52; ws[O_WTT+id] = (d<50)? Wt[d*FT+f] : 0.f; return; }
  id -= 19968;
  if (id < 19968){ int f=id/52, d=id%52; ws[O_WIT+id] = (f<383 && d<50)? Wi[d*FI+f] : 0.f; return; }
  id -= 19968;
  if (id < 10400){ int m=id/52, o=id%52; int t=m/50, d=m%50;
                   ws[O_WIP+id] = (o<50)? Wip[o*200+t*50+d]*g[d] : 0.f; return; }
  id -= 10400;
  if (id < 62400){ int m=id/52, o=id%52; int i=m/50, d=m%50;
                   ws[O_WTP+id] = (o<50)? Wtp[o*1200+i*50+d]*g[d] : 0.f; return; }
  id -= 62400;
  if (id < 50000){ int e=id/100, k=id%100; ws[O_W1T+id] = W1[k*1000+e]; return; }
  id -= 50000;
  if (id < 50000){ int k=id/500, e=id%500; ws[O_W3T+id] = W3[e*100+k]; return; }
  id -= 50000;
  if (id < 208){ int t=id/52, o=id%52; float s=0;
                 if (o<50) for(int d=0;d<50;d++) s += Wip[o*200+t*50+d]*g[d];
                 ws[O_SIP+id]=s; return; }
  id -= 208;
  if (id < 1248){ int i=id/52, o=id%52; float s=0;
                  if (o<50) for(int d=0;d<50;d++) s += Wtp[o*1200+i*50+d]*g[d];
                  ws[O_STP+id]=s; return; }
  id -= 1248;
  if (id < 52){ int o=id; float s=0;
                if (o<50){ for(int j=0;j<200;j++) s += lb[j%50]*Wip[o*200+j]; s=2.f*s+bip[o]; }
                ws[O_CBI+o]=s; return; }
  id -= 52;
  if (id < 52){ int o=id; float s=0;
                if (o<50){ for(int j=0;j<1200;j++) s += lb[j%50]*Wtp[o*1200+j]; s=2.f*s+btp[o]; }
                ws[O_CBT+o]=s; return; }
}

// ---------------- per-batch relation gates ----------------
__global__ void k_rel(const int* ps, const float* rele, const float* Wr1, const float* br1,
                      const float* Wr2, const float* br2, const float* W1, float* ws){
  __shared__ float relL[EE];
  int b = blockIdx.x;
  int r = ps[b*3+1];
  for (int e=threadIdx.x; e<EE; e+=256) relL[e] = rele[(size_t)r*EE+e];
  __syncthreads();
  for (int j=threadIdx.x; j<292; j+=256){
    if (j<96){
      float a=br1[j]; const float* w=&Wr1[j*EE];
      for(int e=0;e<EE;e++) a+=relL[e]*w[e];
      ws[O_RGI+b*96+j]=sigm(a);
    } else if (j<192){
      int jj=j-96; float a=br2[jj]; const float* w=&Wr2[jj*EE];
      for(int e=0;e<EE;e++) a+=relL[e]*w[e];
      ws[O_RGT+b*96+jj]=sigm(a);
    } else {
      int k=j-192; float a=0; const float* w=&W1[k*1000+500];
      for(int e=0;e<EE;e++) a+=relL[e]*w[e];
      ws[O_RB+b*100+k]=a;
    }
  }
}

// ---------------- A[n,k] = ent @ W1[:, :E]^T ----------------
__global__ void k_A(const float* ent, float* ws){
  __shared__ float entL[8*EE];
  int n0 = blockIdx.x*8;
  for (int idx=threadIdx.x; idx<8*EE; idx+=256) entL[idx] = ent[(size_t)n0*EE + idx];
  __syncthreads();
  const float* W1T = &ws[O_W1T];
  for (int idx=threadIdx.x; idx<800; idx+=256){
    int rr=idx/100, k=idx%100; float a=0;
    const float* el=&entL[rr*EE];
    for (int e=0;e<EE;e++) a += el[e]*W1T[e*100+k];
    ws[O_A + (size_t)(n0+rr)*100 + k] = a;
  }
}

// ---------------- pos_t vectors ----------------
__global__ void k_pos(const int* ps, const float* ent, const float* b1, const float* b3, float* ws){
  __shared__ float hL[KH];
  __shared__ float red[4];
  int b=blockIdx.x; int n=ps[b*3+2]; int tid=threadIdx.x;
  if (tid<KH) hL[tid] = leaky(ws[O_A+(size_t)n*100+tid] + ws[O_RB+b*100+tid] + b1[tid]);
  __syncthreads();
  const float* w3t=&ws[O_W3T];
  float sq=0;
  for (int e=tid; e<EE; e+=256){
    float a=b3[e];
    for (int k=0;k<KH;k++) a += hL[k]*w3t[k*500+e];
    float gg=sigm(a); float ta=ent[(size_t)n*EE+e]*gg;
    ws[O_PT+b*500+e]=ta; sq+=ta*ta;
  }
  for (int off=1; off<64; off<<=1) sq += __shfl_xor(sq, off);
  if ((tid&63)==0) red[tid>>6]=sq;
  __syncthreads();
  if (tid==0) ws[O_PTN+b] = sqrtf(red[0]+red[1]+red[2]+red[3]);
}

// ---------------- embedding GEMM: one row/lane, W chunks in LDS ----------------
__global__ __launch_bounds__(256) void k_emb(const float* X, const float* Wp, const float* bias,
                                             float* emb, int R, int F, int rowsPerN, int rowOff,
                                             int xstride){
  __shared__ __align__(16) float Wl[128*52];
  int row = blockIdx.x*256 + threadIdx.x;
  bool act = row < R;
  float4 acc[13];
  #pragma unroll
  for (int c=0;c<13;c++) acc[c]=make_float4(0,0,0,0);
  const float* xr = X + (size_t)(act?row:0)*xstride;
  for (int f0=0; f0<F; f0+=128){
    int nf = min(128, F-f0);
    __syncthreads();
    for (int j=threadIdx.x; j<nf*52; j+=256) Wl[j] = Wp[(size_t)f0*52 + j];
    __syncthreads();
    if (act){
      for (int f=0; f<nf; ++f){
        float x = xr[f0+f];
        const float4* wr = (const float4*)&Wl[f*52];
        #pragma unroll
        for (int c=0;c<13;++c){
          float4 w=wr[c];
          acc[c].x+=x*w.x; acc[c].y+=x*w.y; acc[c].z+=x*w.z; acc[c].w+=x*w.w;
        }
      }
    }
  }
  if (act){
    int n = row / rowsPerN, rr = row % rowsPerN;
    float* dst = emb + (size_t)n*1456 + (size_t)(rowOff+rr)*52;
    #pragma unroll
    for (int c=0;c<13;++c){
      float4 v=acc[c]; int o=c*4;
      v.x=leaky(v.x+bias[o]); v.y=leaky(v.y+bias[o+1]);
      if (c<12){ v.z=leaky(v.z+bias[o+2]); v.w=leaky(v.w+bias[o+3]); }
      else { v.z=0.f; v.w=0.f; }
      *(float4*)&dst[o]=v;
    }
  }
}

// ---------------- fused per-n kernel (mode 0: all n; mode 1: pos rows per b) ----------------
__global__ __launch_bounds__(256) void k_main(const int* ps, float* ws, float* out, int mode){
  __shared__ __align__(16) float teie[1456];
  __shared__ __align__(16) float Pm[120*52];
  __shared__ __align__(16) float Um[120*32];
  __shared__ __align__(16) float Gi[576];
  __shared__ __align__(16) float crs[96];
  __shared__ __align__(16) float aimg[96], atxt[96];
  __shared__ __align__(16) float part1[96], part2[96];
  __shared__ __align__(16) float aU[120];
  __shared__ __align__(16) float PattC[52], QattC[52];
  __shared__ float Gts[16], mimg[24], mtxt[4];
  __shared__ float muA1[4], muA2[24];
  __shared__ float accD1[32], accN1[32], accD2[32], accN2[32];

  int tid = threadIdx.x;
  int bstar = blockIdx.x;
  int n = mode ? ps[bstar*3+2] : blockIdx.x;

  // P0: stage emb row block, zero accumulators
  const float* embn = &ws[O_EMB + (size_t)n*1456];
  for (int j=tid; j<364; j+=256) *(float4*)&teie[j*4] = *(const float4*)&embn[j*4];
  if (tid<32){ accD1[tid]=0.f; accN1[tid]=0.f; accD2[tid]=0.f; accN2[tid]=0.f; }
  __syncthreads();

  // P1: Gram matrices, cross, means
  for (int it=tid; it<716; it+=256){
    if (it<576){
      int i=it/24, j=it%24; float s=0;
      const float* a=&teie[(4+i)*52]; const float* b=&teie[(4+j)*52];
      for(int d=0;d<50;d++) s+=a[d]*b[d];
      Gi[it]=s;
    } else if (it<672){
      int c=it-576; int i=c>>2, t=c&3; float s=0;
      const float* a=&teie[(4+i)*52]; const float* b=&teie[t*52];
      for(int d=0;d<50;d++) s+=a[d]*b[d];
      crs[c]=s;
    } else if (it<688){
      int c=it-672; int t=c>>2, u=c&3; float s=0;
      const float* a=&teie[t*52]; const float* b=&teie[u*52];
      for(int d=0;d<50;d++) s+=a[d]*b[d];
      Gts[c]=s;
    } else if (it<712){
      int i=it-688; float s=0; const float* a=&teie[(4+i)*52];
      for(int d=0;d<50;d++) s+=a[d];
      mimg[i]=s*0.02f;
    } else {
      int t=it-712; float s=0; const float* a=&teie[t*52];
      for(int d=0;d<50;d++) s+=a[d];
      mtxt[t]=s*0.02f;
    }
  }
  __syncthreads();

  // P2: attention softmaxes + means
  if (tid<4){
    int t=tid;
    float mx=-1e30f; for(int i=0;i<24;i++) mx=fmaxf(mx,crs[i*4+t]);
    float ex[24]; float s=0;
    for(int i=0;i<24;i++){ ex[i]=__expf(crs[i*4+t]-mx); s+=ex[i]; }
    float inv=1.f/s; float mu=0;
    for(int i=0;i<24;i++){ float a=ex[i]*inv; aimg[i*4+t]=a; mu+=a*mimg[i]; }
    muA1[t]=mu;
  } else if (tid>=64 && tid<88){
    int i=tid-64;
    float mx=-1e30f; for(int t=0;t<4;t++) mx=fmaxf(mx,crs[i*4+t]);
    float ex[4]; float s=0;
    for(int t=0;t<4;t++){ ex[t]=__expf(crs[i*4+t]-mx); s+=ex[t]; }
    float inv=1.f/s; float mu=0;
    for(int t=0;t<4;t++){ float a=ex[t]*inv; atxt[i*4+t]=a; mu+=a*mtxt[t]; }
    muA2[i]=mu;
  }
  __syncthreads();

  // P3: build P = ipb rows [z=t*24+i][52] + Sip rows; att quadratic partials
  const float* WIPg=&ws[O_WIP];
  for (int it=tid; it<1248; it+=256){
    int z=it/13, q=it%13; int t=z/24, i=z%24;
    const float* wb=&WIPg[(size_t)(t*50)*52 + q*4];
    const float* ieb=&teie[(4+i)*52];
    float4 a=make_float4(0,0,0,0);
    for (int d=0; d<50; ++d){
      float e=ieb[d];
      float4 w=*(const float4*)&wb[(size_t)d*52];
      a.x+=e*w.x; a.y+=e*w.y; a.z+=e*w.z; a.w+=e*w.w;
    }
    *(float4*)&Pm[z*52+q*4]=a;
  }
  for (int j=tid; j<208; j+=256) Pm[96*52+j]=ws[O_SIP+j];
  if (tid<96){
    int i=tid>>2, t=tid&3;
    float s=0; for(int j=0;j<24;j++) s+=Gi[i*24+j]*aimg[j*4+t];
    part1[tid]=aimg[tid]*s;
  } else if (tid<192){
    int c=tid-96; int t=c&3;
    float s=0; for(int u=0;u<4;u++) s+=Gts[t*4+u]*atxt[(c&~3)+u];
    part2[c]=atxt[c]*s;
  }
  __syncthreads();

  // P4: img LN stats -> U ; att aU
  if (tid<128){
    int b=tid&31, t=tid>>5;
    float w1r[24];
    for(int i=0;i<24;i++) w1r[i]=ws[O_RGI+b*96+i*4+t]*crs[i*4+t];
    float mu=0; for(int i=0;i<24;i++) mu+=w1r[i]*mimg[i];
    float q=0;
    for(int i=0;i<24;i++){ float s=0; for(int j=0;j<24;j++) s+=Gi[i*24+j]*w1r[j]; q+=w1r[i]*s; }
    float inv=rsqrtf(q*0.02f-mu*mu+1e-5f);
    for(int i=0;i<24;i++) Um[(t*24+i)*32+b]=inv*w1r[i];
    Um[(96+t)*32+b]=-inv*mu;
  } else if (tid<228){
    int z=tid-128;
    int t=(z<96)? (z/24) : (z-96);
    float q=0; for(int i=0;i<24;i++) q+=part1[i*4+t];
    float inv=rsqrtf(q*0.02f-muA1[t]*muA1[t]+1e-5f);
    aU[z]=(z<96)? inv*aimg[(z%24)*4+t] : -inv*muA1[t];
  }
  __syncthreads();

  // P4b: PattC
  if (tid<52){
    float s=ws[O_CBI+tid];
    for(int z=0;z<100;z++) s+=aU[z]*Pm[z*52+tid];
    PattC[tid]=s;
  }
  __syncthreads();

  // P5: img GEMM + fused cos-sim partials
  {
    int b=tid&31, q0=tid>>5;
    bool h2=(q0+8)<13;
    float4 a0=make_float4(0,0,0,0), a1=make_float4(0,0,0,0);
    #pragma unroll 4
    for (int z=0; z<100; ++z){
      float u=Um[z*32+b];
      float4 p0=*(const float4*)&Pm[z*52+q0*4];
      a0.x+=u*p0.x; a0.y+=u*p0.y; a0.z+=u*p0.z; a0.w+=u*p0.w;
      if (h2){
        float4 p1=*(const float4*)&Pm[z*52+(q0+8)*4];
        a1.x+=u*p1.x; a1.y+=u*p1.y; a1.z+=u*p1.z; a1.w+=u*p1.w;
      }
    }
    float4 c0=*(const float4*)&PattC[q0*4];
    a0.x+=c0.x; a0.y+=c0.y; a0.z+=c0.z; a0.w+=c0.w;
    if (h2){ float4 c1=*(const float4*)&PattC[(q0+8)*4]; a1.x+=c1.x; a1.y+=c1.y; a1.z+=c1.z; a1.w+=c1.w; }
    float ni=a0.x*a0.x+a0.y*a0.y+a0.z*a0.z+a0.w*a0.w;
    if (h2) ni+=a1.x*a1.x+a1.y*a1.y+a1.z*a1.z+a1.w*a1.w;
    if (!mode){
      const float* pv=&ws[O_PIM+b*52];
      float4 p0=*(const float4*)&pv[q0*4];
      float di=a0.x*p0.x+a0.y*p0.y+a0.z*p0.z+a0.w*p0.w;
      if (h2){
        float4 p1=*(const float4*)&pv[(q0+8)*4];
        di+=a1.x*p1.x+a1.y*p1.y+a1.z*p1.z+a1.w*p1.w;
      }
      atomicAdd(&accD1[b],di); atomicAdd(&accN1[b],ni);
    } else {
      atomicAdd(&accN1[b],ni);
      if (b==bstar){
        *(float4*)&ws[O_PIM+b*52+q0*4]=a0;
        if (h2) *(float4*)&ws[O_PIM+b*52+(q0+8)*4]=a1;
      }
    }
  }
  __syncthreads();

  // P6: write img sims / norms; build P = tpb + Stp rows
  if (!mode){
    if (tid<32)
      out[(size_t)BN + (size_t)tid*NN + n] = accD1[tid]/(sqrtf(accN1[tid])*ws[O_PIMN+tid]+1e-10f);
  } else {
    if (tid==0) ws[O_PIMN+bstar]=sqrtf(accN1[bstar]);
  }
  {
    const float* WTPg=&ws[O_WTP];
    for (int it=tid; it<1248; it+=256){
      int z=it/13, q=it%13; int t=z/24, i=z%24;
      const float* wb=&WTPg[(size_t)(i*50)*52 + q*4];
      const float* teb=&teie[t*52];
      float4 a=make_float4(0,0,0,0);
      for (int d=0; d<50; ++d){
        float e=teb[d];
        float4 w=*(const float4*)&wb[(size_t)d*52];
        a.x+=e*w.x; a.y+=e*w.y; a.z+=e*w.z; a.w+=e*w.w;
      }
      *(float4*)&Pm[z*52+q*4]=a;
    }
    for (int j=tid; j<1248; j+=256) Pm[96*52+j]=ws[O_STP+j];
  }
  __syncthreads();

  // P7: text LN stats -> U ; att aU2
  for (int it=tid; it<888; it+=256){
    if (it<768){
      int b=it&31, i=it>>5;
      float w2r[4];
      for(int t=0;t<4;t++) w2r[t]=ws[O_RGT+b*96+i*4+t]*crs[i*4+t];
      float mu=0; for(int t=0;t<4;t++) mu+=w2r[t]*mtxt[t];
      float q=0;
      for(int t=0;t<4;t++){ float s=0; for(int u=0;u<4;u++) s+=Gts[t*4+u]*w2r[u]; q+=w2r[t]*s; }
      float inv=rsqrtf(q*0.02f-mu*mu+1e-5f);
      for(int t=0;t<4;t++) Um[(t*24+i)*32+b]=inv*w2r[t];
      Um[(96+i)*32+b]=-inv*mu;
    } else {
      int z=it-768;
      int i=(z<96)? (z%24) : (z-96);
      float q=0; for(int t=0;t<4;t++) q+=part2[i*4+t];
      float inv=rsqrtf(q*0.02f-muA2[i]*muA2[i]+1e-5f);
      aU[z]=(z<96)? inv*atxt[(z%24)*4+(z/24)] : -inv*muA2[i];
    }
  }
  __syncthreads();

  // P7b: QattC
  if (tid<52){
    float s=ws[O_CBT+tid];
    for(int z=0;z<120;z++) s+=aU[z]*Pm[z*52+tid];
    QattC[tid]=s;
  }
  __syncthreads();

  // P8: text GEMM + fused cos-sim partials
  {
    int b=tid&31, q0=tid>>5;
    bool h2=(q0+8)<13;
    float4 a0=make_float4(0,0,0,0), a1=make_float4(0,0,0,0);
    #pragma unroll 4
    for (int z=0; z<120; ++z){
      float u=Um[z*32+b];
      float4 p0=*(const float4*)&Pm[z*52+q0*4];
      a0.x+=u*p0.x; a0.y+=u*p0.y; a0.z+=u*p0.z; a0.w+=u*p0.w;
      if (h2){
        float4 p1=*(const float4*)&Pm[z*52+(q0+8)*4];
        a1.x+=u*p1.x; a1.y+=u*p1.y; a1.z+=u*p1.z; a1.w+=u*p1.w;
      }
    }
    float4 c0=*(const float4*)&QattC[q0*4];
    a0.x+=c0.x; a0.y+=c0.y; a0.z+=c0.z; a0.w+=c0.w;
    if (h2){ float4 c1=*(const float4*)&QattC[(q0+8)*4]; a1.x+=c1.x; a1.y+=c1.y; a1.z+=c1.z; a1.w+=c1.w; }
    float ni=a0.x*a0.x+a0.y*a0.y+a0.z*a0.z+a0.w*a0.w;
    if (h2) ni+=a1.x*a1.x+a1.y*a1.y+a1.z*a1.z+a1.w*a1.w;
    if (!mode){
      const float* pv=&ws[O_PTX+b*52];
      float4 p0=*(const float4*)&pv[q0*4];
      float di=a0.x*p0.x+a0.y*p0.y+a0.z*p0.z+a0.w*p0.w;
      if (h2){
        float4 p1=*(const float4*)&pv[(q0+8)*4];
        di+=a1.x*p1.x+a1.y*p1.y+a1.z*p1.z+a1.w*p1.w;
      }
      atomicAdd(&accD2[b],di); atomicAdd(&accN2[b],ni);
    } else {
      atomicAdd(&accN2[b],ni);
      if (b==bstar){
        *(float4*)&ws[O_PTX+b*52+q0*4]=a0;
        if (h2) *(float4*)&ws[O_PTX+b*52+(q0+8)*4]=a1;
      }
    }
  }
  __syncthreads();

  // P9: write text sims / norms
  if (!mode){
    if (tid<32)
      out[2*(size_t)BN + (size_t)tid*NN + n] = accD2[tid]/(sqrtf(accN2[tid])*ws[O_PTXN+tid]+1e-10f);
  } else {
    if (tid==0) ws[O_PTXN+bstar]=sqrtf(accN2[bstar]);
  }
}

// ---------------- fused gate GEMM + t-path cos-sim ----------------
__global__ __launch_bounds__(256) void k_gate(const float* ent, const float* b1, const float* b3,
                                              float* ws, float* out){
  __shared__ float entL[EE];
  __shared__ float AL[KH];
  __shared__ float hall[BB*KH];
  __shared__ __align__(16) float w3c[KH*100];
  __shared__ float numL[BB], sqL[BB];
  int n=blockIdx.x, tid=threadIdx.x;
  for (int e=tid;e<EE;e+=256) entL[e]=ent[(size_t)n*EE+e];
  if (tid<KH) AL[tid]=ws[O_A+(size_t)n*KH+tid];
  if (tid<BB){ numL[tid]=0.f; sqL[tid]=0.f; }
  __syncthreads();
  for (int idx=tid; idx<BB*KH; idx+=256){
    int b=idx/KH, k=idx%KH;
    hall[idx]=leaky(AL[k]+ws[O_RB+b*KH+k]+b1[k]);
  }
  __syncthreads();
  int e4=tid&31, bsub=tid>>5;
  const float* W3T=&ws[O_W3T];
  const float* PT=&ws[O_PT];
  bool val = e4<25;
  int j0=e4*4;
  for (int c=0;c<5;c++){
    int ebase=c*100;
    for (int idx=tid; idx<10000; idx+=256){
      int k=idx/100, j=idx%100;
      w3c[idx]=W3T[k*500+ebase+j];
    }
    __syncthreads();
    for (int bb=0; bb<4; bb++){
      int b=bb*8+bsub;
      float a0=0,a1=0,a2=0,a3=0;
      if (val){
        const float* hb=&hall[b*KH];
        for (int k=0;k<KH;k++){
          float hv=hb[k];
          const float4 w4=*(const float4*)&w3c[k*100+j0];
          a0+=hv*w4.x; a1+=hv*w4.y; a2+=hv*w4.z; a3+=hv*w4.w;
        }
      }
      float pn=0, psq=0;
      if (val){
        int e=ebase+j0;
        float g0=sigm(a0+b3[e+0]); float t0=entL[e+0]*g0; pn+=t0*PT[b*EE+e+0]; psq+=t0*t0;
        float g1=sigm(a1+b3[e+1]); float t1=entL[e+1]*g1; pn+=t1*PT[b*EE+e+1]; psq+=t1*t1;
        float g2=sigm(a2+b3[e+2]); float t2=entL[e+2]*g2; pn+=t2*PT[b*EE+e+2]; psq+=t2*t2;
        float g3=sigm(a3+b3[e+3]); float t3=entL[e+3]*g3; pn+=t3*PT[b*EE+e+3]; psq+=t3*t3;
      }
      for (int off=1; off<32; off<<=1){ pn+=__shfl_xor(pn,off); psq+=__shfl_xor(psq,off); }
      if (e4==0){ atomicAdd(&numL[b],pn); atomicAdd(&sqL[b],psq); }
    }
    __syncthreads();
  }
  if (tid<BB){
    out[3*(size_t)BN + (size_t)tid*NN + n] = numL[tid]/(sqrtf(sqL[tid])*ws[O_PTN+tid]+1e-10f);
  }
}

// ---------------- softmax pass 1 ----------------
__global__ void k_smax1(const float* out, float* ws){
  __shared__ float red[4];
  __shared__ float Msh;
  int a=blockIdx.x>>5, b=blockIdx.x&31, tid=threadIdx.x;
  const float* arr=&out[(size_t)(1+a)*BN + (size_t)b*NN];
  float mx=-1e30f;
  for (int i=tid;i<NN;i+=256) mx=fmaxf(mx,arr[i]);
  for (int off=1;off<64;off<<=1) mx=fmaxf(mx,__shfl_xor(mx,off));
  if ((tid&63)==0) red[tid>>6]=mx;
  __syncthreads();
  if (tid==0) Msh=fmaxf(fmaxf(red[0],red[1]),fmaxf(red[2],red[3]));
  __syncthreads();
  float M2=2.f*Msh;
  float s=0;
  for (int i=tid;i<NN;i+=256) s+=__expf(2.f*arr[i]-M2);
  for (int off=1;off<64;off<<=1) s+=__shfl_xor(s,off);
  if ((tid&63)==0) red[tid>>6]=s;
  __syncthreads();
  if (tid==0){ ws[O_MR+a*32+b]=M2; ws[O_SR+a*32+b]=red[0]+red[1]+red[2]+red[3]; }
}

// ---------------- softmax pass 2 ----------------
__global__ void k_smax2(float* out, const float* ws){
  int t=blockIdx.x*256+threadIdx.x;
  if (t>=BN) return;
  int b=t/NN;
  float r=0;
  for (int a=0;a<3;a++)
    r += __expf(2.f*out[(size_t)(1+a)*BN+t]-ws[O_MR+a*32+b])/ws[O_SR+a*32+b];
  out[t]=r;
}

extern "C" void kernel_launch(void* const* d_in, const int* in_sizes, int n_in,
                              void* d_out, int out_size, void* d_ws, size_t ws_size,
                              hipStream_t stream){
  (void)in_sizes; (void)n_in; (void)out_size; (void)ws_size;
  const int*   ps  =(const int*)  d_in[0];
  const float* etg =(const float*)d_in[1];
  const float* eig =(const float*)d_in[2];
  const float* ent =(const float*)d_in[3];
  const float* rele=(const float*)d_in[4];
  const float* Wt  =(const float*)d_in[5];
  const float* btx =(const float*)d_in[6];
  const float* Wi  =(const float*)d_in[7];
  const float* bim =(const float*)d_in[8];
  const float* Wtp =(const float*)d_in[9];
  const float* btp =(const float*)d_in[10];
  const float* Wip =(const float*)d_in[11];
  const float* bip =(const float*)d_in[12];
  const float* Wr1 =(const float*)d_in[13];
  const float* br1 =(const float*)d_in[14];
  const float* Wr2 =(const float*)d_in[15];
  const float* br2 =(const float*)d_in[16];
  const float* W1  =(const float*)d_in[17];
  const float* b1  =(const float*)d_in[18];
  const float* W3  =(const float*)d_in[19];
  const float* b3  =(const float*)d_in[20];
  const float* lng =(const float*)d_in[21];
  const float* lnb =(const float*)d_in[22];
  float* ws =(float*)d_ws;
  float* out=(float*)d_out;

  k_prep <<<838,256,0,stream>>>(Wt,Wi,Wip,Wtp,W1,W3,lng,lnb,bip,btp,ws);
  k_rel  <<<32, 256,0,stream>>>(ps,rele,Wr1,br1,Wr2,br2,W1,ws);
  k_A    <<<625,256,0,stream>>>(ent,ws);
  k_pos  <<<32, 256,0,stream>>>(ps,ent,b1,b3,ws);
  k_emb  <<<79, 256,0,stream>>>(etg,&ws[O_WTT],btx,&ws[O_EMB],20000,FT,4,0,FT);
  k_emb  <<<469,256,0,stream>>>(eig,&ws[O_WIT],bim,&ws[O_EMB],120000,FI,24,4,FI);
  k_main <<<32,  256,0,stream>>>(ps,ws,out,1);
  k_main <<<5000,256,0,stream>>>(ps,ws,out,0);
  k_gate <<<5000,256,0,stream>>>(ent,b1,b3,ws,out);
  k_smax1<<<96, 256,0,stream>>>(out,ws);
  k_smax2<<<625,256,0,stream>>>(out,ws);
}

// Round 3
// 1779.330 us; speedup vs baseline: 1.8122x; 1.0726x over previous
//
#include <hip/hip_runtime.h>
#include <math.h>

#define BB 32
#define NN 5000
#define EE 500
#define AT 50
#define TTT 4
#define ITT 24
#define FT 384
#define FI 383
#define KH 100
#define BN (BB*NN)

__device__ __forceinline__ float leaky(float x){ return x > 0.f ? x : 0.1f*x; }
__device__ __forceinline__ float sigm(float x){ return 1.f/(1.f+__expf(-x)); }

// workspace offsets (floats). Total 8,023,256 floats = 32.1 MB.
enum : size_t {
  O_WTT = 0,         // 19968  W_text^T padded [f][52]
  O_WIT = 19968,     // 19968  W_img^T padded [f][52] (row 383 zero)
  O_WIP = 39936,     // 10400  W_iproj*g padded [t*50+d][52]
  O_WTP = 50336,     // 62400  W_tproj*g padded [i*50+d][52]
  O_W1T = 112736,    // 50000  W1[:, :E]^T [e][100]
  O_W3T = 162736,    // 50000  W3^T [k][500]
  O_SIP = 212736,    // 208    sum_d Wg_iproj [t][52]
  O_STP = 212944,    // 1248   sum_d Wg_tproj [i][52]
  O_CBI = 214192,    // 52     2*sum(lnb*W_iproj)+b_iproj, pad 0
  O_CBT = 214244,    // 52
  O_RGI = 214296,    // 3072   sigmoid(rel@Wrel1^T+b) [b][96]
  O_RGT = 217368,    // 3072
  O_RB  = 220440,    // 3200   rel@W1[:,E:]^T [b][100]
  O_A   = 223640,    // 500000 ent@W1[:,:E]^T [n][100]
  O_PT  = 723640,    // 16000  pos_t [b][500]
  O_PTN = 739640,    // 32
  O_PIM = 739672,    // 1664   pos_img [b][52]
  O_PIMN= 741336,    // 32
  O_PTX = 741368,    // 1664
  O_PTXN= 743032,    // 32
  O_MR  = 743064,    // 96
  O_SR  = 743160,    // 96
  O_EMB = 743256,    // 7280000 emb [n][28][52]: rows 0..3 text, 4..27 img
};

// ---------------- weight preprocessing ----------------
__global__ void k_prep(const float* Wt, const float* Wi, const float* Wip, const float* Wtp,
                       const float* W1, const float* W3, const float* g, const float* lb,
                       const float* bip, const float* btp, float* ws){
  int id = blockIdx.x*256 + threadIdx.x;
  if (id < 19968){ int f=id/52, d=id%52; ws[O_WTT+id] = (d<50)? Wt[d*FT+f] : 0.f; return; }
  id -= 19968;
  if (id < 19968){ int f=id/52, d=id%52; ws[O_WIT+id] = (f<383 && d<50)? Wi[d*FI+f] : 0.f; return; }
  id -= 19968;
  if (id < 10400){ int m=id/52, o=id%52; int t=m/50, d=m%50;
                   ws[O_WIP+id] = (o<50)? Wip[o*200+t*50+d]*g[d] : 0.f; return; }
  id -= 10400;
  if (id < 62400){ int m=id/52, o=id%52; int i=m/50, d=m%50;
                   ws[O_WTP+id] = (o<50)? Wtp[o*1200+i*50+d]*g[d] : 0.f; return; }
  id -= 62400;
  if (id < 50000){ int e=id/100, k=id%100; ws[O_W1T+id] = W1[k*1000+e]; return; }
  id -= 50000;
  if (id < 50000){ int k=id/500, e=id%500; ws[O_W3T+id] = W3[e*100+k]; return; }
  id -= 50000;
  if (id < 208){ int t=id/52, o=id%52; float s=0;
                 if (o<50) for(int d=0;d<50;d++) s += Wip[o*200+t*50+d]*g[d];
                 ws[O_SIP+id]=s; return; }
  id -= 208;
  if (id < 1248){ int i=id/52, o=id%52; float s=0;
                  if (o<50) for(int d=0;d<50;d++) s += Wtp[o*1200+i*50+d]*g[d];
                  ws[O_STP+id]=s; return; }
  id -= 1248;
  if (id < 52){ int o=id; float s=0;
                if (o<50){ for(int j=0;j<200;j++) s += lb[j%50]*Wip[o*200+j]; s=2.f*s+bip[o]; }
                ws[O_CBI+o]=s; return; }
  id -= 52;
  if (id < 52){ int o=id; float s=0;
                if (o<50){ for(int j=0;j<1200;j++) s += lb[j%50]*Wtp[o*1200+j]; s=2.f*s+btp[o]; }
                ws[O_CBT+o]=s; return; }
}

// ---------------- per-batch relation gates ----------------
__global__ void k_rel(const int* ps, const float* rele, const float* Wr1, const float* br1,
                      const float* Wr2, const float* br2, const float* W1, float* ws){
  __shared__ float relL[EE];
  int b = blockIdx.x;
  int r = ps[b*3+1];
  for (int e=threadIdx.x; e<EE; e+=256) relL[e] = rele[(size_t)r*EE+e];
  __syncthreads();
  for (int j=threadIdx.x; j<292; j+=256){
    if (j<96){
      float a=br1[j]; const float* w=&Wr1[j*EE];
      for(int e=0;e<EE;e++) a+=relL[e]*w[e];
      ws[O_RGI+b*96+j]=sigm(a);
    } else if (j<192){
      int jj=j-96; float a=br2[jj]; const float* w=&Wr2[jj*EE];
      for(int e=0;e<EE;e++) a+=relL[e]*w[e];
      ws[O_RGT+b*96+jj]=sigm(a);
    } else {
      int k=j-192; float a=0; const float* w=&W1[k*1000+500];
      for(int e=0;e<EE;e++) a+=relL[e]*w[e];
      ws[O_RB+b*100+k]=a;
    }
  }
}

// ---------------- A[n,k] = ent @ W1[:, :E]^T ----------------
__global__ void k_A(const float* ent, float* ws){
  __shared__ float entL[8*EE];
  int n0 = blockIdx.x*8;
  for (int idx=threadIdx.x; idx<8*EE; idx+=256) entL[idx] = ent[(size_t)n0*EE + idx];
  __syncthreads();
  const float* W1T = &ws[O_W1T];
  for (int idx=threadIdx.x; idx<800; idx+=256){
    int rr=idx/100, k=idx%100; float a=0;
    const float* el=&entL[rr*EE];
    for (int e=0;e<EE;e++) a += el[e]*W1T[e*100+k];
    ws[O_A + (size_t)(n0+rr)*100 + k] = a;
  }
}

// ---------------- pos_t vectors ----------------
__global__ void k_pos(const int* ps, const float* ent, const float* b1, const float* b3, float* ws){
  __shared__ float hL[KH];
  __shared__ float red[4];
  int b=blockIdx.x; int n=ps[b*3+2]; int tid=threadIdx.x;
  if (tid<KH) hL[tid] = leaky(ws[O_A+(size_t)n*100+tid] + ws[O_RB+b*100+tid] + b1[tid]);
  __syncthreads();
  const float* w3t=&ws[O_W3T];
  float sq=0;
  for (int e=tid; e<EE; e+=256){
    float a=b3[e];
    for (int k=0;k<KH;k++) a += hL[k]*w3t[k*500+e];
    float gg=sigm(a); float ta=ent[(size_t)n*EE+e]*gg;
    ws[O_PT+b*500+e]=ta; sq+=ta*ta;
  }
  for (int off=1; off<64; off<<=1) sq += __shfl_xor(sq, off);
  if ((tid&63)==0) red[tid>>6]=sq;
  __syncthreads();
  if (tid==0) ws[O_PTN+b] = sqrtf(red[0]+red[1]+red[2]+red[3]);
}

// ---------------- embedding GEMM: one row/lane, W chunks in LDS ----------------
__global__ __launch_bounds__(256) void k_emb(const float* X, const float* Wp, const float* bias,
                                             float* emb, int R, int F, int rowsPerN, int rowOff,
                                             int xstride){
  __shared__ __align__(16) float Wl[128*52];
  int row = blockIdx.x*256 + threadIdx.x;
  bool act = row < R;
  float4 acc[13];
  #pragma unroll
  for (int c=0;c<13;c++) acc[c]=make_float4(0,0,0,0);
  const float* xr = X + (size_t)(act?row:0)*xstride;
  for (int f0=0; f0<F; f0+=128){
    int nf = min(128, F-f0);
    __syncthreads();
    for (int j=threadIdx.x; j<nf*52; j+=256) Wl[j] = Wp[(size_t)f0*52 + j];
    __syncthreads();
    if (act){
      for (int f=0; f<nf; ++f){
        float x = xr[f0+f];
        const float4* wr = (const float4*)&Wl[f*52];
        #pragma unroll
        for (int c=0;c<13;++c){
          float4 w=wr[c];
          acc[c].x+=x*w.x; acc[c].y+=x*w.y; acc[c].z+=x*w.z; acc[c].w+=x*w.w;
        }
      }
    }
  }
  if (act){
    int n = row / rowsPerN, rr = row % rowsPerN;
    float* dst = emb + (size_t)n*1456 + (size_t)(rowOff+rr)*52;
    #pragma unroll
    for (int c=0;c<13;++c){
      float4 v=acc[c]; int o=c*4;
      v.x=leaky(v.x+bias[o]); v.y=leaky(v.y+bias[o+1]);
      if (c<12){ v.z=leaky(v.z+bias[o+2]); v.w=leaky(v.w+bias[o+3]); }
      else { v.z=0.f; v.w=0.f; }
      *(float4*)&dst[o]=v;
    }
  }
}

// ---------------- fused per-n kernel (mode 0: all n; mode 1: pos rows per b) ----------------
__global__ __launch_bounds__(256) void k_main(const int* ps, float* ws, float* out, int mode){
  __shared__ __align__(16) float teie[1456];
  __shared__ __align__(16) float Pm[120*52];
  __shared__ __align__(16) float Um[120*32];
  __shared__ __align__(16) float Gi[576];
  __shared__ __align__(16) float crs[96];
  __shared__ __align__(16) float aimg[96], atxt[96];
  __shared__ __align__(16) float part1[96], part2[96];
  __shared__ __align__(16) float aU[120];
  __shared__ __align__(16) float PattC[52], QattC[52];
  __shared__ float Gts[16], mimg[24], mtxt[4];
  __shared__ float muA1[4], muA2[24];
  __shared__ float accD1[32], accN1[32], accD2[32], accN2[32];

  int tid = threadIdx.x;
  int bstar = blockIdx.x;
  int n = mode ? ps[bstar*3+2] : blockIdx.x;

  // P0: stage emb row block, zero accumulators
  const float* embn = &ws[O_EMB + (size_t)n*1456];
  for (int j=tid; j<364; j+=256) *(float4*)&teie[j*4] = *(const float4*)&embn[j*4];
  if (tid<32){ accD1[tid]=0.f; accN1[tid]=0.f; accD2[tid]=0.f; accN2[tid]=0.f; }
  __syncthreads();

  // P1: Gram matrices, cross, means
  for (int it=tid; it<716; it+=256){
    if (it<576){
      int i=it/24, j=it%24; float s=0;
      const float* a=&teie[(4+i)*52]; const float* b=&teie[(4+j)*52];
      for(int d=0;d<50;d++) s+=a[d]*b[d];
      Gi[it]=s;
    } else if (it<672){
      int c=it-576; int i=c>>2, t=c&3; float s=0;
      const float* a=&teie[(4+i)*52]; const float* b=&teie[t*52];
      for(int d=0;d<50;d++) s+=a[d]*b[d];
      crs[c]=s;
    } else if (it<688){
      int c=it-672; int t=c>>2, u=c&3; float s=0;
      const float* a=&teie[t*52]; const float* b=&teie[u*52];
      for(int d=0;d<50;d++) s+=a[d]*b[d];
      Gts[c]=s;
    } else if (it<712){
      int i=it-688; float s=0; const float* a=&teie[(4+i)*52];
      for(int d=0;d<50;d++) s+=a[d];
      mimg[i]=s*0.02f;
    } else {
      int t=it-712; float s=0; const float* a=&teie[t*52];
      for(int d=0;d<50;d++) s+=a[d];
      mtxt[t]=s*0.02f;
    }
  }
  __syncthreads();

  // P2: attention softmaxes + means
  if (tid<4){
    int t=tid;
    float mx=-1e30f; for(int i=0;i<24;i++) mx=fmaxf(mx,crs[i*4+t]);
    float ex[24]; float s=0;
    for(int i=0;i<24;i++){ ex[i]=__expf(crs[i*4+t]-mx); s+=ex[i]; }
    float inv=1.f/s; float mu=0;
    for(int i=0;i<24;i++){ float a=ex[i]*inv; aimg[i*4+t]=a; mu+=a*mimg[i]; }
    muA1[t]=mu;
  } else if (tid>=64 && tid<88){
    int i=tid-64;
    float mx=-1e30f; for(int t=0;t<4;t++) mx=fmaxf(mx,crs[i*4+t]);
    float ex[4]; float s=0;
    for(int t=0;t<4;t++){ ex[t]=__expf(crs[i*4+t]-mx); s+=ex[t]; }
    float inv=1.f/s; float mu=0;
    for(int t=0;t<4;t++){ float a=ex[t]*inv; atxt[i*4+t]=a; mu+=a*mtxt[t]; }
    muA2[i]=mu;
  }
  __syncthreads();

  // P3: build P = ipb rows [z=t*24+i][52] + Sip rows; att quadratic partials
  const float* WIPg=&ws[O_WIP];
  for (int it=tid; it<1248; it+=256){
    int z=it/13, q=it%13; int t=z/24, i=z%24;
    const float* wb=&WIPg[(size_t)(t*50)*52 + q*4];
    const float* ieb=&teie[(4+i)*52];
    float4 a=make_float4(0,0,0,0);
    for (int d=0; d<50; ++d){
      float e=ieb[d];
      float4 w=*(const float4*)&wb[(size_t)d*52];
      a.x+=e*w.x; a.y+=e*w.y; a.z+=e*w.z; a.w+=e*w.w;
    }
    *(float4*)&Pm[z*52+q*4]=a;
  }
  for (int j=tid; j<208; j+=256) Pm[96*52+j]=ws[O_SIP+j];
  if (tid<96){
    int i=tid>>2, t=tid&3;
    float s=0; for(int j=0;j<24;j++) s+=Gi[i*24+j]*aimg[j*4+t];
    part1[tid]=aimg[tid]*s;
  } else if (tid<192){
    int c=tid-96; int t=c&3;
    float s=0; for(int u=0;u<4;u++) s+=Gts[t*4+u]*atxt[(c&~3)+u];
    part2[c]=atxt[c]*s;
  }
  __syncthreads();

  // P4: img LN stats -> U ; att aU
  if (tid<128){
    int b=tid&31, t=tid>>5;
    float w1r[24];
    for(int i=0;i<24;i++) w1r[i]=ws[O_RGI+b*96+i*4+t]*crs[i*4+t];
    float mu=0; for(int i=0;i<24;i++) mu+=w1r[i]*mimg[i];
    float q=0;
    for(int i=0;i<24;i++){ float s=0; for(int j=0;j<24;j++) s+=Gi[i*24+j]*w1r[j]; q+=w1r[i]*s; }
    float inv=rsqrtf(q*0.02f-mu*mu+1e-5f);
    for(int i=0;i<24;i++) Um[(t*24+i)*32+b]=inv*w1r[i];
    Um[(96+t)*32+b]=-inv*mu;
  } else if (tid<228){
    int z=tid-128;
    int t=(z<96)? (z/24) : (z-96);
    float q=0; for(int i=0;i<24;i++) q+=part1[i*4+t];
    float inv=rsqrtf(q*0.02f-muA1[t]*muA1[t]+1e-5f);
    aU[z]=(z<96)? inv*aimg[(z%24)*4+t] : -inv*muA1[t];
  }
  __syncthreads();

  // P4b: PattC
  if (tid<52){
    float s=ws[O_CBI+tid];
    for(int z=0;z<100;z++) s+=aU[z]*Pm[z*52+tid];
    PattC[tid]=s;
  }
  __syncthreads();

  // P5: img GEMM + fused cos-sim partials
  {
    int b=tid&31, q0=tid>>5;
    bool h2=(q0+8)<13;
    float4 a0=make_float4(0,0,0,0), a1=make_float4(0,0,0,0);
    #pragma unroll 4
    for (int z=0; z<100; ++z){
      float u=Um[z*32+b];
      float4 p0=*(const float4*)&Pm[z*52+q0*4];
      a0.x+=u*p0.x; a0.y+=u*p0.y; a0.z+=u*p0.z; a0.w+=u*p0.w;
      if (h2){
        float4 p1=*(const float4*)&Pm[z*52+(q0+8)*4];
        a1.x+=u*p1.x; a1.y+=u*p1.y; a1.z+=u*p1.z; a1.w+=u*p1.w;
      }
    }
    float4 c0=*(const float4*)&PattC[q0*4];
    a0.x+=c0.x; a0.y+=c0.y; a0.z+=c0.z; a0.w+=c0.w;
    if (h2){ float4 c1=*(const float4*)&PattC[(q0+8)*4]; a1.x+=c1.x; a1.y+=c1.y; a1.z+=c1.z; a1.w+=c1.w; }
    float ni=a0.x*a0.x+a0.y*a0.y+a0.z*a0.z+a0.w*a0.w;
    if (h2) ni+=a1.x*a1.x+a1.y*a1.y+a1.z*a1.z+a1.w*a1.w;
    if (!mode){
      const float* pv=&ws[O_PIM+b*52];
      float4 p0=*(const float4*)&pv[q0*4];
      float di=a0.x*p0.x+a0.y*p0.y+a0.z*p0.z+a0.w*p0.w;
      if (h2){
        float4 p1=*(const float4*)&pv[(q0+8)*4];
        di+=a1.x*p1.x+a1.y*p1.y+a1.z*p1.z+a1.w*p1.w;
      }
      atomicAdd(&accD1[b],di); atomicAdd(&accN1[b],ni);
    } else {
      atomicAdd(&accN1[b],ni);
      if (b==bstar){
        *(float4*)&ws[O_PIM+b*52+q0*4]=a0;
        if (h2) *(float4*)&ws[O_PIM+b*52+(q0+8)*4]=a1;
      }
    }
  }
  __syncthreads();

  // P6: write img sims / norms; build P = tpb + Stp rows
  if (!mode){
    if (tid<32)
      out[(size_t)BN + (size_t)tid*NN + n] = accD1[tid]/(sqrtf(accN1[tid])*ws[O_PIMN+tid]+1e-10f);
  } else {
    if (tid==0) ws[O_PIMN+bstar]=sqrtf(accN1[bstar]);
  }
  {
    const float* WTPg=&ws[O_WTP];
    for (int it=tid; it<1248; it+=256){
      int z=it/13, q=it%13; int t=z/24, i=z%24;
      const float* wb=&WTPg[(size_t)(i*50)*52 + q*4];
      const float* teb=&teie[t*52];
      float4 a=make_float4(0,0,0,0);
      for (int d=0; d<50; ++d){
        float e=teb[d];
        float4 w=*(const float4*)&wb[(size_t)d*52];
        a.x+=e*w.x; a.y+=e*w.y; a.z+=e*w.z; a.w+=e*w.w;
      }
      *(float4*)&Pm[z*52+q*4]=a;
    }
    for (int j=tid; j<1248; j+=256) Pm[96*52+j]=ws[O_STP+j];
  }
  __syncthreads();

  // P7: text LN stats -> U ; att aU2
  for (int it=tid; it<888; it+=256){
    if (it<768){
      int b=it&31, i=it>>5;
      float w2r[4];
      for(int t=0;t<4;t++) w2r[t]=ws[O_RGT+b*96+i*4+t]*crs[i*4+t];
      float mu=0; for(int t=0;t<4;t++) mu+=w2r[t]*mtxt[t];
      float q=0;
      for(int t=0;t<4;t++){ float s=0; for(int u=0;u<4;u++) s+=Gts[t*4+u]*w2r[u]; q+=w2r[t]*s; }
      float inv=rsqrtf(q*0.02f-mu*mu+1e-5f);
      for(int t=0;t<4;t++) Um[(t*24+i)*32+b]=inv*w2r[t];
      Um[(96+i)*32+b]=-inv*mu;
    } else {
      int z=it-768;
      int i=(z<96)? (z%24) : (z-96);
      float q=0; for(int t=0;t<4;t++) q+=part2[i*4+t];
      float inv=rsqrtf(q*0.02f-muA2[i]*muA2[i]+1e-5f);
      aU[z]=(z<96)? inv*atxt[(z%24)*4+(z/24)] : -inv*muA2[i];
    }
  }
  __syncthreads();

  // P7b: QattC
  if (tid<52){
    float s=ws[O_CBT+tid];
    for(int z=0;z<120;z++) s+=aU[z]*Pm[z*52+tid];
    QattC[tid]=s;
  }
  __syncthreads();

  // P8: text GEMM + fused cos-sim partials
  {
    int b=tid&31, q0=tid>>5;
    bool h2=(q0+8)<13;
    float4 a0=make_float4(0,0,0,0), a1=make_float4(0,0,0,0);
    #pragma unroll 4
    for (int z=0; z<120; ++z){
      float u=Um[z*32+b];
      float4 p0=*(const float4*)&Pm[z*52+q0*4];
      a0.x+=u*p0.x; a0.y+=u*p0.y; a0.z+=u*p0.z; a0.w+=u*p0.w;
      if (h2){
        float4 p1=*(const float4*)&Pm[z*52+(q0+8)*4];
        a1.x+=u*p1.x; a1.y+=u*p1.y; a1.z+=u*p1.z; a1.w+=u*p1.w;
      }
    }
    float4 c0=*(const float4*)&QattC[q0*4];
    a0.x+=c0.x; a0.y+=c0.y; a0.z+=c0.z; a0.w+=c0.w;
    if (h2){ float4 c1=*(const float4*)&QattC[(q0+8)*4]; a1.x+=c1.x; a1.y+=c1.y; a1.z+=c1.z; a1.w+=c1.w; }
    float ni=a0.x*a0.x+a0.y*a0.y+a0.z*a0.z+a0.w*a0.w;
    if (h2) ni+=a1.x*a1.x+a1.y*a1.y+a1.z*a1.z+a1.w*a1.w;
    if (!mode){
      const float* pv=&ws[O_PTX+b*52];
      float4 p0=*(const float4*)&pv[q0*4];
      float di=a0.x*p0.x+a0.y*p0.y+a0.z*p0.z+a0.w*p0.w;
      if (h2){
        float4 p1=*(const float4*)&pv[(q0+8)*4];
        di+=a1.x*p1.x+a1.y*p1.y+a1.z*p1.z+a1.w*p1.w;
      }
      atomicAdd(&accD2[b],di); atomicAdd(&accN2[b],ni);
    } else {
      atomicAdd(&accN2[b],ni);
      if (b==bstar){
        *(float4*)&ws[O_PTX+b*52+q0*4]=a0;
        if (h2) *(float4*)&ws[O_PTX+b*52+(q0+8)*4]=a1;
      }
    }
  }
  __syncthreads();

  // P9: write text sims / norms
  if (!mode){
    if (tid<32)
      out[2*(size_t)BN + (size_t)tid*NN + n] = accD2[tid]/(sqrtf(accN2[tid])*ws[O_PTXN+tid]+1e-10f);
  } else {
    if (tid==0) ws[O_PTXN+bstar]=sqrtf(accN2[bstar]);
  }
}

// ---------------- fused gate GEMM + t-path cos-sim: 4e x 4b register tile ----------------
__global__ __launch_bounds__(256) void k_gate(const float* ent, const float* b1, const float* b3,
                                              float* ws, float* out){
  __shared__ float entL[EE];
  __shared__ float b3L[EE];
  __shared__ __align__(16) float hallT[KH*32];   // [k][b]   12.8 KB
  __shared__ __align__(16) float w3c[KH*100];    // [k][j]   40 KB (e-chunk)
  __shared__ __align__(16) float PTc[BB*100];    // [b][j]   12.8 KB (e-chunk)
  __shared__ float numL[BB], sqL[BB];
  int n=blockIdx.x, tid=threadIdx.x;

  for (int e=tid; e<EE; e+=256){ entL[e]=ent[(size_t)n*EE+e]; b3L[e]=b3[e]; }
  if (tid<BB){ numL[tid]=0.f; sqL[tid]=0.f; }
  for (int idx=tid; idx<KH*32; idx+=256){
    int k=idx>>5, b=idx&31;
    hallT[idx] = leaky(ws[O_A+(size_t)n*KH+k] + ws[O_RB+b*KH+k] + b1[k]);
  }

  int eslot=tid&31, bslot=tid>>5;          // 8 bslots x 4 b = 32 b, one pass
  bool val = eslot<25;                     // 25 x 4 = 100 e per chunk
  int j0 = (val? eslot:0)*4;
  float pn0=0,pn1=0,pn2=0,pn3=0, ps0=0,ps1=0,ps2=0,ps3=0;
  const float* W3T=&ws[O_W3T];
  const float* PT=&ws[O_PT];

  for (int c=0;c<5;c++){
    __syncthreads();
    for (int idx=tid; idx<10000; idx+=256){
      int k=idx/100, j=idx%100;
      w3c[idx]=W3T[(size_t)k*500 + c*100 + j];
    }
    for (int idx=tid; idx<3200; idx+=256){
      int b=idx/100, j=idx%100;
      PTc[idx]=PT[(size_t)b*EE + c*100 + j];
    }
    __syncthreads();

    float4 a0=make_float4(0,0,0,0), a1=make_float4(0,0,0,0);
    float4 a2=make_float4(0,0,0,0), a3=make_float4(0,0,0,0);
    const float4* wr=(const float4*)&w3c[j0];      // stride 25 float4 per k
    const float4* hr=(const float4*)&hallT[bslot*4]; // stride 8 float4 per k
    #pragma unroll 4
    for (int k=0;k<KH;k++){
      float4 w=wr[(size_t)k*25];
      float4 h=hr[(size_t)k*8];
      a0.x+=h.x*w.x; a0.y+=h.x*w.y; a0.z+=h.x*w.z; a0.w+=h.x*w.w;
      a1.x+=h.y*w.x; a1.y+=h.y*w.y; a1.z+=h.y*w.z; a1.w+=h.y*w.w;
      a2.x+=h.z*w.x; a2.y+=h.z*w.y; a2.z+=h.z*w.z; a2.w+=h.z*w.w;
      a3.x+=h.w*w.x; a3.y+=h.w*w.y; a3.z+=h.w*w.z; a3.w+=h.w*w.w;
    }
    if (val){
      float4 bb4=*(const float4*)&b3L[c*100+j0];
      float4 ee4=*(const float4*)&entL[c*100+j0];
      float4 p0=*(const float4*)&PTc[(bslot*4+0)*100+j0];
      float4 p1=*(const float4*)&PTc[(bslot*4+1)*100+j0];
      float4 p2=*(const float4*)&PTc[(bslot*4+2)*100+j0];
      float4 p3=*(const float4*)&PTc[(bslot*4+3)*100+j0];
      float t;
      t=ee4.x*sigm(a0.x+bb4.x); pn0+=t*p0.x; ps0+=t*t;
      t=ee4.y*sigm(a0.y+bb4.y); pn0+=t*p0.y; ps0+=t*t;
      t=ee4.z*sigm(a0.z+bb4.z); pn0+=t*p0.z; ps0+=t*t;
      t=ee4.w*sigm(a0.w+bb4.w); pn0+=t*p0.w; ps0+=t*t;
      t=ee4.x*sigm(a1.x+bb4.x); pn1+=t*p1.x; ps1+=t*t;
      t=ee4.y*sigm(a1.y+bb4.y); pn1+=t*p1.y; ps1+=t*t;
      t=ee4.z*sigm(a1.z+bb4.z); pn1+=t*p1.z; ps1+=t*t;
      t=ee4.w*sigm(a1.w+bb4.w); pn1+=t*p1.w; ps1+=t*t;
      t=ee4.x*sigm(a2.x+bb4.x); pn2+=t*p2.x; ps2+=t*t;
      t=ee4.y*sigm(a2.y+bb4.y); pn2+=t*p2.y; ps2+=t*t;
      t=ee4.z*sigm(a2.z+bb4.z); pn2+=t*p2.z; ps2+=t*t;
      t=ee4.w*sigm(a2.w+bb4.w); pn2+=t*p2.w; ps2+=t*t;
      t=ee4.x*sigm(a3.x+bb4.x); pn3+=t*p3.x; ps3+=t*t;
      t=ee4.y*sigm(a3.y+bb4.y); pn3+=t*p3.y; ps3+=t*t;
      t=ee4.z*sigm(a3.z+bb4.z); pn3+=t*p3.z; ps3+=t*t;
      t=ee4.w*sigm(a3.w+bb4.w); pn3+=t*p3.w; ps3+=t*t;
    }
  }
  // reduce over the 32 eslots (stay within 32-lane half: offsets 1..16)
  for (int off=1; off<32; off<<=1){
    pn0+=__shfl_xor(pn0,off); ps0+=__shfl_xor(ps0,off);
    pn1+=__shfl_xor(pn1,off); ps1+=__shfl_xor(ps1,off);
    pn2+=__shfl_xor(pn2,off); ps2+=__shfl_xor(ps2,off);
    pn3+=__shfl_xor(pn3,off); ps3+=__shfl_xor(ps3,off);
  }
  if (eslot==0){
    int b0=bslot*4;
    atomicAdd(&numL[b0+0],pn0); atomicAdd(&sqL[b0+0],ps0);
    atomicAdd(&numL[b0+1],pn1); atomicAdd(&sqL[b0+1],ps1);
    atomicAdd(&numL[b0+2],pn2); atomicAdd(&sqL[b0+2],ps2);
    atomicAdd(&numL[b0+3],pn3); atomicAdd(&sqL[b0+3],ps3);
  }
  __syncthreads();
  if (tid<BB){
    out[3*(size_t)BN + (size_t)tid*NN + n] = numL[tid]/(sqrtf(sqL[tid])*ws[O_PTN+tid]+1e-10f);
  }
}

// ---------------- softmax pass 1 ----------------
__global__ void k_smax1(const float* out, float* ws){
  __shared__ float red[4];
  __shared__ float Msh;
  int a=blockIdx.x>>5, b=blockIdx.x&31, tid=threadIdx.x;
  const float* arr=&out[(size_t)(1+a)*BN + (size_t)b*NN];
  float mx=-1e30f;
  for (int i=tid;i<NN;i+=256) mx=fmaxf(mx,arr[i]);
  for (int off=1;off<64;off<<=1) mx=fmaxf(mx,__shfl_xor(mx,off));
  if ((tid&63)==0) red[tid>>6]=mx;
  __syncthreads();
  if (tid==0) Msh=fmaxf(fmaxf(red[0],red[1]),fmaxf(red[2],red[3]));
  __syncthreads();
  float M2=2.f*Msh;
  float s=0;
  for (int i=tid;i<NN;i+=256) s+=__expf(2.f*arr[i]-M2);
  for (int off=1;off<64;off<<=1) s+=__shfl_xor(s,off);
  if ((tid&63)==0) red[tid>>6]=s;
  __syncthreads();
  if (tid==0){ ws[O_MR+a*32+b]=M2; ws[O_SR+a*32+b]=red[0]+red[1]+red[2]+red[3]; }
}

// ---------------- softmax pass 2 ----------------
__global__ void k_smax2(float* out, const float* ws){
  int t=blockIdx.x*256+threadIdx.x;
  if (t>=BN) return;
  int b=t/NN;
  float r=0;
  for (int a=0;a<3;a++)
    r += __expf(2.f*out[(size_t)(1+a)*BN+t]-ws[O_MR+a*32+b])/ws[O_SR+a*32+b];
  out[t]=r;
}

extern "C" void kernel_launch(void* const* d_in, const int* in_sizes, int n_in,
                              void* d_out, int out_size, void* d_ws, size_t ws_size,
                              hipStream_t stream){
  (void)in_sizes; (void)n_in; (void)out_size; (void)ws_size;
  const int*   ps  =(const int*)  d_in[0];
  const float* etg =(const float*)d_in[1];
  const float* eig =(const float*)d_in[2];
  const float* ent =(const float*)d_in[3];
  const float* rele=(const float*)d_in[4];
  const float* Wt  =(const float*)d_in[5];
  const float* btx =(const float*)d_in[6];
  const float* Wi  =(const float*)d_in[7];
  const float* bim =(const float*)d_in[8];
  const float* Wtp =(const float*)d_in[9];
  const float* btp =(const float*)d_in[10];
  const float* Wip =(const float*)d_in[11];
  const float* bip =(const float*)d_in[12];
  const float* Wr1 =(const float*)d_in[13];
  const float* br1 =(const float*)d_in[14];
  const float* Wr2 =(const float*)d_in[15];
  const float* br2 =(const float*)d_in[16];
  const float* W1  =(const float*)d_in[17];
  const float* b1  =(const float*)d_in[18];
  const float* W3  =(const float*)d_in[19];
  const float* b3  =(const float*)d_in[20];
  const float* lng =(const float*)d_in[21];
  const float* lnb =(const float*)d_in[22];
  float* ws =(float*)d_ws;
  float* out=(float*)d_out;

  k_prep <<<838,256,0,stream>>>(Wt,Wi,Wip,Wtp,W1,W3,lng,lnb,bip,btp,ws);
  k_rel  <<<32, 256,0,stream>>>(ps,rele,Wr1,br1,Wr2,br2,W1,ws);
  k_A    <<<625,256,0,stream>>>(ent,ws);
  k_pos  <<<32, 256,0,stream>>>(ps,ent,b1,b3,ws);
  k_emb  <<<79, 256,0,stream>>>(etg,&ws[O_WTT],btx,&ws[O_EMB],20000,FT,4,0,FT);
  k_emb  <<<469,256,0,stream>>>(eig,&ws[O_WIT],bim,&ws[O_EMB],120000,FI,24,4,FI);
  k_main <<<32,  256,0,stream>>>(ps,ws,out,1);
  k_main <<<5000,256,0,stream>>>(ps,ws,out,0);
  k_gate <<<5000,256,0,stream>>>(ent,b1,b3,ws,out);
  k_smax1<<<96, 256,0,stream>>>(out,ws);
  k_smax2<<<625,256,0,stream>>>(out,ws);
}